// Round 5
// baseline (204.090 us; speedup 1.0000x reference)
//
#include <hip/hip_runtime.h>
#include <cmath>

// Shapes fixed by the reference: data [32,128,80,80] int32, scale 0.0625.
#define NB  32
#define NC  128
#define NHW 6400          // 80*80, contiguous per (b,c)
#define TPB 64            // ONE wave per block; lane = one pixel

typedef float vfloat4 __attribute__((ext_vector_type(4)));

// ---------------------------------------------------------------------------
// Setup kernel: build the two 256-entry LUTs once into d_ws.
// EXACT math of the verified in-block LUT builder (absmax 0.0 in round 3).
// 4 blocks x 64 threads; entry index = blockIdx*64 + tid.
// ---------------------------------------------------------------------------
__global__ __launch_bounds__(64) void lut_build_kernel(
    int* __restrict__ exp_ws, float* __restrict__ rec_ws,
    const float* __restrict__ dscale) {
#pragma clang fp contract(off)
  const int t = blockIdx.x * 64 + threadIdx.x;   // 0..255
  const float ds = dscale[0];

  const float EXP_SCALE_F = (float)(2.0 / 65535.0);
  float x = (float)(-t) * ds;
  float e;
  if (x >= 0.0f) {
    float y0 = expf(0.0f), y1 = expf(1.0f);
    e = rintf((y0 + x * ((y1 - y0) / 1.0f)) / EXP_SCALE_F);
  } else if (x >= -10.0f) {
    float delta = 10.0f / 255.0f;
    float idxf = rintf((x + 10.0f) * 25.5f);
    idxf = fminf(fmaxf(idxf, 0.0f), 255.0f);
    float xs = -10.0f + idxf * delta;
    e = rintf((float)exp((double)xs) / EXP_SCALE_F);
  } else {
    float delta = 10.0f / 255.0f;
    float idxf = rintf((x + 20.0f) * 25.5f);
    idxf = fminf(fmaxf(idxf, 0.0f), 255.0f);
    float xs = -20.0f + idxf * delta;
    e = rintf((float)exp((double)xs) / EXP_SCALE_F);
  }
  e = fminf(fmaxf(e, -32768.0f), 32767.0f);
  exp_ws[t] = (int)e;

  const float RECIP_SCALE_F = (float)((1.0 / 0.1) * 2.0 / 65535.0);
  float deltar = (250.0f - 0.1f) / 255.0f;
  float xs = 0.1f + (float)t * deltar;
  float r = rintf((1.0f / xs) / RECIP_SCALE_F);
  r = fminf(fmaxf(r, -32768.0f), 32767.0f);
  rec_ws[t] = r;
}

// ---------------------------------------------------------------------------
// Main kernel. Streaming, reduction-free: lane = pixel hw0 + t.
// Pass A: 128 strided dword loads (each wave-instr = 256 B contiguous of one
//         channel row), per-lane running int max. No cross-lane anything.
// Pass B: reload (L2/L3-hit: this wave's 32 KB footprint was just fetched),
//         gather exp from LDS LUT, per-lane sum, keep exp packed u16x2 in
//         pe[64] (fully unrolled -> static indices, stays in VGPRs).
// Then per-lane recip + 64x-unrolled NT store loop.
// Loads/stores spread over the WHOLE body -> memory pipe continuously fed
// (the champion's phase-burst structure starved it; see round-4 postmortem).
// No barriers at all (single wave; LDS ordering is program-order).
// ---------------------------------------------------------------------------
__global__ __launch_bounds__(TPB) void qsoftmax_kernel(
    const int* __restrict__ data,
    const int* __restrict__ exp_ws,
    const float* __restrict__ rec_ws,
    float* __restrict__ out) {
#pragma clang fp contract(off)
  __shared__ int   exp_tab[256];    // quantized exp as function of j = qmax - data
  __shared__ float recip_tab[256];  // quantized 1/v table, region (0.1, 250)

  const int t = threadIdx.x;        // 0..63 = lane = pixel offset in tile

  // ---- stage LUTs from global (built by lut_build_kernel); wave-local,
  //      program-order visibility, no barrier needed ----
  {
    int4   ev = ((const int4*)exp_ws)[t];      // entries 4t..4t+3
    float4 rv = ((const float4*)rec_ws)[t];
    ((int4*)exp_tab)[t]     = ev;
    ((float4*)recip_tab)[t] = rv;
  }

  const int blk = blockIdx.x;               // 0..3199, one 64-pixel tile
  const int b   = blk / (NHW / TPB);        // /100
  const int hw  = (blk % (NHW / TPB)) * TPB + t;   // this lane's pixel
  const int* gp = data + b * NC * NHW + hw;        // channel-0 element

  // ---- pass A: per-lane running max over the 128 channels ----
  int m = -128;
#pragma unroll 32
  for (int c = 0; c < NC; ++c) {
    m = max(m, gp[c * NHW]);
  }

  // ---- pass B: reload (cache-hit), gather exp, sum, keep packed ----
  // j = m - v is guaranteed in [0,255]: v <= m (per-pixel max), both in
  // [-128,127]. Identical to the champion's byte-unpacked indexing.
  int pe[NC / 2];                   // packed exp, 2 channels per int
  int ssum = 0;
#pragma unroll
  for (int c = 0; c < NC; c += 2) {
    int v0 = gp[c * NHW];
    int v1 = gp[(c + 1) * NHW];
    int e0 = exp_tab[m - v0];
    int e1 = exp_tab[m - v1];
    ssum += e0;
    ssum += e1;
    pe[c >> 1] = e0 | (e1 << 16);   // e in [0,32767] -> fits u16, sign-safe
  }

  // ---- per-lane recip (exact champion math) ----
  const float DIV_SCALE_F = (float)((2.0 / 65535.0) * 128.0); // exp_scale * 2^7
  const float RIDX_K_F    = (float)(255.0 / (250.0 - 0.1));
  float rq;
  {
    float ss = rintf((float)ssum * 0.0078125f);
    ss = fminf(fmaxf(ss, -32768.0f), 32767.0f);
    float v = ss * DIV_SCALE_F;
    float idxf = rintf((v - 0.1f) * RIDX_K_F);
    idxf = fminf(fmaxf(idxf, 0.0f), 255.0f);
    rq = recip_tab[(int)idxf];
  }

  // ---- epilogue: out = clip(round((e*r)*K), -128, 127) * OUT_SCALE ----
  const float K_F = (float)((2.0 / 65535.0) * ((1.0 / 0.1) * 2.0 / 65535.0) / (2.0 / 255.0));
  const float OUT_SCALE_F = (float)(2.0 / 255.0);
  float* op = out + b * NC * NHW + hw;
#pragma unroll
  for (int c = 0; c < NC; c += 2) {
    int p = pe[c >> 1];
    float e0 = (float)(p & 0xFFFF);
    float e1 = (float)((unsigned)p >> 16);
    float o0 = fminf(fmaxf(rintf((e0 * rq) * K_F), -128.0f), 127.0f) * OUT_SCALE_F;
    float o1 = fminf(fmaxf(rintf((e1 * rq) * K_F), -128.0f), 127.0f) * OUT_SCALE_F;
    __builtin_nontemporal_store(o0, &op[c * NHW]);
    __builtin_nontemporal_store(o1, &op[(c + 1) * NHW]);
  }
}

extern "C" void kernel_launch(void* const* d_in, const int* in_sizes, int n_in,
                              void* d_out, int out_size, void* d_ws, size_t ws_size,
                              hipStream_t stream) {
  const int* data     = (const int*)d_in[0];
  const float* dscale = (const float*)d_in[1];
  float* out          = (float*)d_out;
  (void)in_sizes; (void)n_in; (void)out_size; (void)ws_size;

  int*   exp_ws = (int*)d_ws;                       // 256 x int
  float* rec_ws = (float*)((char*)d_ws + 1024);     // 256 x float

  lut_build_kernel<<<dim3(4), dim3(64), 0, stream>>>(exp_ws, rec_ws, dscale);
  qsoftmax_kernel<<<dim3(NB * (NHW / TPB)), dim3(TPB), 0, stream>>>(
      data, exp_ws, rec_ws, out);
}

// Round 7
// 196.386 us; speedup vs baseline: 1.0392x; 1.0392x over previous
//
#include <hip/hip_runtime.h>
#include <cmath>

// Shapes fixed by the reference: data [32,128,80,80] int32, scale 0.0625.
#define NB   32
#define NC   128
#define NHW  6400         // 80*80, contiguous per (b,c)
#define TILE 256          // pixels per block
#define TPB  256          // 4 waves; wave w owns channels {w, w+4, ..., w+124}

typedef float vfloat4 __attribute__((ext_vector_type(4)));

// ---------------------------------------------------------------------------
// Setup kernel: build the two 256-entry LUTs once into d_ws.
// EXACT math of the verified in-block LUT builder (absmax 0.0, rounds 3/5).
// ---------------------------------------------------------------------------
__global__ __launch_bounds__(64) void lut_build_kernel(
    int* __restrict__ exp_ws, float* __restrict__ rec_ws,
    const float* __restrict__ dscale) {
#pragma clang fp contract(off)
  const int t = blockIdx.x * 64 + threadIdx.x;   // 0..255
  const float ds = dscale[0];

  const float EXP_SCALE_F = (float)(2.0 / 65535.0);
  float x = (float)(-t) * ds;
  float e;
  if (x >= 0.0f) {
    float y0 = expf(0.0f), y1 = expf(1.0f);
    e = rintf((y0 + x * ((y1 - y0) / 1.0f)) / EXP_SCALE_F);
  } else if (x >= -10.0f) {
    float delta = 10.0f / 255.0f;
    float idxf = rintf((x + 10.0f) * 25.5f);
    idxf = fminf(fmaxf(idxf, 0.0f), 255.0f);
    float xs = -10.0f + idxf * delta;
    e = rintf((float)exp((double)xs) / EXP_SCALE_F);
  } else {
    float delta = 10.0f / 255.0f;
    float idxf = rintf((x + 20.0f) * 25.5f);
    idxf = fminf(fmaxf(idxf, 0.0f), 255.0f);
    float xs = -20.0f + idxf * delta;
    e = rintf((float)exp((double)xs) / EXP_SCALE_F);
  }
  e = fminf(fmaxf(e, -32768.0f), 32767.0f);
  exp_ws[t] = (int)e;

  const float RECIP_SCALE_F = (float)((1.0 / 0.1) * 2.0 / 65535.0);
  float deltar = (250.0f - 0.1f) / 255.0f;
  float xs = 0.1f + (float)t * deltar;
  float r = rintf((1.0f / xs) / RECIP_SCALE_F);
  r = fminf(fmaxf(r, -32768.0f), 32767.0f);
  rec_ws[t] = r;
}

// ---------------------------------------------------------------------------
// Main kernel: 3-pass, LDS-staged, 1 KB-contiguous global accesses.
//   wave w (0..3) owns channels {w+4j}, j=0..31
//   lane l (0..63) owns pixels {4l..4l+3} of the 256-px tile
// Pass 1: 32x global int4 load (wave-instr = 1 KB contiguous of one channel
//         row), per-lane running max, pack int8 -> LDS data tile (32 KB).
// Pass 2: LDS re-read (2-way bank alias = free), exp gather, per-lane sum,
//         4-way cross-wave sum reduce, recip.
// Pass 3: LDS re-read, re-gather, epilogue, 1 KB-contiguous float4 NT stores.
// Input is read from HBM exactly once (r5's L2-miss re-read regression fixed).
// ---------------------------------------------------------------------------
__global__ __launch_bounds__(TPB) void qsoftmax_kernel(
    const int* __restrict__ data,
    const int* __restrict__ exp_ws,
    const float* __restrict__ rec_ws,
    float* __restrict__ out) {
#pragma clang fp contract(off)
  __shared__ unsigned int lds_data[NC * 64];  // [c][l] packed 4x int8 (32 KB)
  __shared__ int          exp_tab[256];       // quantized exp, j = qmax - data
  __shared__ float        recip_tab[256];     // quantized 1/v, region (0.1,250)
  __shared__ unsigned int red_mp[4 * 64];     // [wave][lane] packed 4x int8 max
  __shared__ int4         red_s[4][64];       // [wave][lane] partial sums

  const int t = threadIdx.x;
  const int w = t >> 6;                       // wave 0..3
  const int l = t & 63;                       // lane 0..63

  const int blk  = blockIdx.x;                // 0..799
  const int b    = blk / (NHW / TILE);        // /25
  const int hw0  = (blk % (NHW / TILE)) * TILE;
  // int4 index of (b, c=0, pixel 4l):
  const int base4 = b * NC * (NHW / 4) + (hw0 >> 2) + l;

  // ---- stage LUTs from global (built by lut_build_kernel) ----
  exp_tab[t]   = exp_ws[t];
  recip_tab[t] = rec_ws[t];

  // ---- pass 1: load 32 channel rows (1 KB/instr), max, pack to LDS ----
  const int4* g4 = (const int4*)data;
  int4 m = make_int4(-128, -128, -128, -128);
#pragma unroll 8
  for (int j = 0; j < 32; ++j) {
    const int c = w + 4 * j;
    int4 v = g4[base4 + c * (NHW / 4)];
    m.x = max(m.x, v.x); m.y = max(m.y, v.y);
    m.z = max(m.z, v.z); m.w = max(m.w, v.w);
    lds_data[c * 64 + l] = (unsigned)((v.x & 255) | ((v.y & 255) << 8) |
                                      ((v.z & 255) << 16) |
                                      ((unsigned)(v.w & 255) << 24));
  }
  red_mp[w * 64 + l] = (unsigned)((m.x & 255) | ((m.y & 255) << 8) |
                                  ((m.z & 255) << 16) |
                                  ((unsigned)(m.w & 255) << 24));
  __syncthreads();

  // ---- 4-way cross-wave max reduce (per pixel quad) ----
  int4 q = make_int4(-128, -128, -128, -128);
#pragma unroll
  for (int ww = 0; ww < 4; ++ww) {
    unsigned mp = red_mp[ww * 64 + l];
    q.x = max(q.x, (int)(signed char)(mp));
    q.y = max(q.y, (int)(signed char)(mp >> 8));
    q.z = max(q.z, (int)(signed char)(mp >> 16));
    q.w = max(q.w, (int)(signed char)(mp >> 24));
  }

  // ---- pass 2: gather exp from LDS tile, per-lane channel-partial sum ----
  int4 s = make_int4(0, 0, 0, 0);
#pragma unroll 8
  for (int j = 0; j < 32; ++j) {
    const int c = w + 4 * j;
    unsigned pdv = lds_data[c * 64 + l];
    int c0 = (int)(signed char)(pdv);
    int c1 = (int)(signed char)(pdv >> 8);
    int c2 = (int)(signed char)(pdv >> 16);
    int c3 = (int)(signed char)(pdv >> 24);
    s.x += exp_tab[q.x - c0];       // index guaranteed in [0,255]
    s.y += exp_tab[q.y - c1];
    s.z += exp_tab[q.z - c2];
    s.w += exp_tab[q.w - c3];
  }
  red_s[w][l] = s;
  __syncthreads();

  // ---- 4-way cross-wave sum reduce + recip (champion math, exact) ----
  int4 tot = red_s[0][l];
#pragma unroll
  for (int ww = 1; ww < 4; ++ww) {
    int4 r = red_s[ww][l];
    tot.x += r.x; tot.y += r.y; tot.z += r.z; tot.w += r.w;
  }
  const float DIV_SCALE_F = (float)((2.0 / 65535.0) * 128.0); // exp_scale*2^7
  const float RIDX_K_F    = (float)(255.0 / (250.0 - 0.1));
  float rq[4];
  {
    int tv[4] = {tot.x, tot.y, tot.z, tot.w};
#pragma unroll
    for (int jj = 0; jj < 4; ++jj) {
      float ss = rintf((float)tv[jj] * 0.0078125f);
      ss = fminf(fmaxf(ss, -32768.0f), 32767.0f);
      float v = ss * DIV_SCALE_F;
      float idxf = rintf((v - 0.1f) * RIDX_K_F);
      idxf = fminf(fmaxf(idxf, 0.0f), 255.0f);
      rq[jj] = recip_tab[(int)idxf];
    }
  }

  // ---- pass 3: re-gather, epilogue, 1 KB-contiguous NT stores ----
  const float K_F = (float)((2.0 / 65535.0) * ((1.0 / 0.1) * 2.0 / 65535.0) / (2.0 / 255.0));
  const float OUT_SCALE_F = (float)(2.0 / 255.0);
  vfloat4* o4 = (vfloat4*)out;
#pragma unroll 8
  for (int j = 0; j < 32; ++j) {
    const int c = w + 4 * j;
    unsigned pdv = lds_data[c * 64 + l];
    int c0 = (int)(signed char)(pdv);
    int c1 = (int)(signed char)(pdv >> 8);
    int c2 = (int)(signed char)(pdv >> 16);
    int c3 = (int)(signed char)(pdv >> 24);
    float e0 = (float)exp_tab[q.x - c0];
    float e1 = (float)exp_tab[q.y - c1];
    float e2 = (float)exp_tab[q.z - c2];
    float e3 = (float)exp_tab[q.w - c3];
    vfloat4 o;
    o.x = fminf(fmaxf(rintf((e0 * rq[0]) * K_F), -128.0f), 127.0f) * OUT_SCALE_F;
    o.y = fminf(fmaxf(rintf((e1 * rq[1]) * K_F), -128.0f), 127.0f) * OUT_SCALE_F;
    o.z = fminf(fmaxf(rintf((e2 * rq[2]) * K_F), -128.0f), 127.0f) * OUT_SCALE_F;
    o.w = fminf(fmaxf(rintf((e3 * rq[3]) * K_F), -128.0f), 127.0f) * OUT_SCALE_F;
    __builtin_nontemporal_store(o, &o4[base4 + c * (NHW / 4)]);
  }
}

extern "C" void kernel_launch(void* const* d_in, const int* in_sizes, int n_in,
                              void* d_out, int out_size, void* d_ws, size_t ws_size,
                              hipStream_t stream) {
  const int* data     = (const int*)d_in[0];
  const float* dscale = (const float*)d_in[1];
  float* out          = (float*)d_out;
  (void)in_sizes; (void)n_in; (void)out_size; (void)ws_size;

  int*   exp_ws = (int*)d_ws;                       // 256 x int
  float* rec_ws = (float*)((char*)d_ws + 1024);     // 256 x float

  lut_build_kernel<<<dim3(4), dim3(64), 0, stream>>>(exp_ws, rec_ws, dscale);
  qsoftmax_kernel<<<dim3(NB * (NHW / TILE)), dim3(TPB), 0, stream>>>(
      data, exp_ws, rec_ws, out);
}